// Round 11
// baseline (211.549 us; speedup 1.0000x reference)
//
#include <hip/hip_runtime.h>

#define NTOK 4096
#define NCH  256
#define NCS  128
#define NBAT 4

typedef _Float16 f16;
typedef _Float16 f16x8 __attribute__((ext_vector_type(8)));
typedef _Float16 f16x4 __attribute__((ext_vector_type(4)));
typedef __fp16 fp16x2 __attribute__((ext_vector_type(2)));
typedef float f32x16 __attribute__((ext_vector_type(16)));

__device__ __forceinline__ f16 f2h(float f) { return (f16)f; }
__device__ __forceinline__ float h2f(f16 h) { return (float)h; }
__device__ __forceinline__ unsigned short h2s(f16 h) {
  union { f16 h; unsigned short s; } u; u.h = h; return u.s;
}
__device__ __forceinline__ f32x16 mfma32(f16x8 a, f16x8 b, f32x16 c) {
  return __builtin_amdgcn_mfma_f32_32x32x16_f16(a, b, c, 0, 0, 0);
}
__device__ __forceinline__ unsigned pkrtz(float a, float b) {
  union { fp16x2 h; unsigned u; } u;
  u.h = __builtin_amdgcn_cvt_pkrtz(a, b);
  return u.u;
}

// ---------------- 1: weights -> f16 ----------------
__global__ void k_wconv(const float* __restrict__ wq, const float* __restrict__ wk,
                        const float* __restrict__ wv, const float* __restrict__ wo,
                        f16* __restrict__ out) {
  int i = blockIdx.x * 256 + threadIdx.x;   // 131072 total
  int seg = i >> 15, off = i & 32767;
  const float* s = (seg == 0) ? wq : (seg == 1) ? wk : (seg == 2) ? wv : wo;
  out[i] = f2h(s[off]);
}

// ---------------- 2: fused QKV projection (MFMA), 12 waves/block ----------------
// grid (128, 4): 32-token tiles. wave w -> proj p=w>>2 (Q,K,V), out-ch tile nt=w&3.
__launch_bounds__(768)
__global__ void k_qkv(const float* __restrict__ x,
                      const f16* __restrict__ wqb, const f16* __restrict__ wkb,
                      const f16* __restrict__ wvb,
                      const float* __restrict__ bq, const float* __restrict__ bk,
                      const float* __restrict__ bv,
                      f16* __restrict__ Qt, f16* __restrict__ Kt, f16* __restrict__ Vc) {
  __shared__ f16 Xs[32][264];   // [token][c], +8 pad
  const int tid = threadIdx.x;
  const int b = blockIdx.y;
  const int t0 = blockIdx.x * 32;
  // stage X tile: 32 tok x 128 channel-pairs
  for (int idx = tid; idx < 4096; idx += 768) {
    const int tok = idx & 31, cp = idx >> 5;
    const float* xp = x + ((size_t)(b * NCH + 2 * cp)) * NTOK + t0 + tok;
    float f0 = xp[0];
    float f1 = xp[NTOK];
    unsigned pk = (unsigned)h2s(f2h(f0)) | ((unsigned)h2s(f2h(f1)) << 16);
    *(unsigned*)&Xs[tok][2 * cp] = pk;
  }
  __syncthreads();
  const int lane = tid & 63, w = tid >> 6;
  const int p = w >> 2, nt = w & 3;
  const int cc = lane & 31, hi = lane >> 5;
  const f16* wb = (p == 0) ? wqb : (p == 1) ? wkb : wvb;
  const float* bp = (p == 0) ? bq : (p == 1) ? bk : bv;

  f32x16 acc;
  #pragma unroll
  for (int i = 0; i < 16; i++) acc[i] = 0.f;
  #pragma unroll
  for (int ks = 0; ks < 16; ks++) {
    f16x8 a = *(const f16x8*)&Xs[cc][ks * 16 + hi * 8];
    f16x8 bw = *(const f16x8*)(wb + (size_t)(nt * 32 + cc) * NCH + ks * 16 + hi * 8);
    acc = mfma32(a, bw, acc);
  }
  const int oc = nt * 32 + cc;
  const float bias = bp[oc];
  if (p < 2) {   // Q,K token-major [B][N][128]
    f16* dst = (p == 0) ? Qt : Kt;
    #pragma unroll
    for (int i = 0; i < 16; i++) {
      int row = (i & 3) + 8 * (i >> 2) + 4 * hi;
      dst[((size_t)b * NTOK + t0 + row) * NCS + oc] = f2h(acc[i] + bias);
    }
  } else {       // V channel-major [B][128][N]
    #pragma unroll
    for (int q = 0; q < 4; q++) {
      f16x4 pk;
      #pragma unroll
      for (int j = 0; j < 4; j++) pk[j] = f2h(acc[4 * q + j] + bias);
      *(f16x4*)(Vc + ((size_t)b * NCS + oc) * NTOK + t0 + 8 * q + 4 * hi) = pk;
    }
  }
}

// ---------------- 3: flash attention, key-split 8 ways, 4 waves/block ----------------
// LDS double-buffer, one barrier/iter. launch_bounds(256, 1): waves-per-eu min = 1
// -> full 512-reg budget, allocator must NOT spill to chase occupancy (round-10: its
// 128-reg/4-wave heuristic cost ~45 MB scratch; LDS caps us at 2 waves/SIMD anyway).
__launch_bounds__(256, 1)
__global__ void k_attn(const f16* __restrict__ Qt, const f16* __restrict__ Kt,
                       const f16* __restrict__ Vc,
                       f16* __restrict__ OP, float* __restrict__ ML, int niter) {
  __shared__ f16 Ks[2][64][136];    // [buf][key][c], +8 pad
  __shared__ f16 Vs[2][128][72];    // [buf][d][key], +8 pad (V^T)
  __shared__ float als[4][32];
  const int tid = threadIdx.x;
  const int b = blockIdx.x & 3, kh = blockIdx.x >> 2, qt = blockIdx.y;
  const int lane = tid & 63, w = tid >> 6, cc = lane & 31, hi = lane >> 5;

  const f16* qp = Qt + ((size_t)b * NTOK + qt * 128 + w * 32 + cc) * NCS + hi * 8;
  f16x8 qf[8];
  #pragma unroll
  for (int ks = 0; ks < 8; ks++) qf[ks] = *(const f16x8*)(qp + ks * 16);

  f32x16 o[4];
  #pragma unroll
  for (int nt = 0; nt < 4; nt++)
    #pragma unroll
    for (int i = 0; i < 16; i++) o[nt][i] = 0.f;
  float m = -1e30f, l = 0.f;

  const int kkey = tid >> 2, kcb = (tid & 3) * 32;   // K staging map (256 thr)
  const int vd = tid >> 1, vh = (tid & 1) * 32;      // V staging map
  const int kb0 = kh * niter * 64;
  const f16* kbase = Kt + ((size_t)b * NTOK + kkey) * NCS + kcb;
  const f16* vbase = Vc + ((size_t)b * NCS + vd) * NTOK + vh;

  // prologue: stage tile 0 into buffer 0
  {
    const f16* kp = kbase + (size_t)kb0 * NCS;
    const f16* vp = vbase + kb0;
    #pragma unroll
    for (int pp = 0; pp < 4; pp++) {
      *(int4*)&Ks[0][kkey][kcb + pp * 8] = *(const int4*)(kp + pp * 8);
      *(int4*)&Vs[0][vd][vh + pp * 8] = *(const int4*)(vp + pp * 8);
    }
  }
  __syncthreads();

  for (int it = 0; it < niter; it++) {
    const int cur = it & 1;
    // issue next-tile loads NOW; they complete during compute below
    int4 kr0, kr1, kr2, kr3, vr0, vr1, vr2, vr3;
    const bool pf = (it + 1 < niter);
    if (pf) {
      const int kb = kb0 + (it + 1) * 64;
      const f16* kp = kbase + (size_t)kb * NCS;
      const f16* vp = vbase + kb;
      kr0 = *(const int4*)(kp);      kr1 = *(const int4*)(kp + 8);
      kr2 = *(const int4*)(kp + 16); kr3 = *(const int4*)(kp + 24);
      vr0 = *(const int4*)(vp);      vr1 = *(const int4*)(vp + 8);
      vr2 = *(const int4*)(vp + 16); vr3 = *(const int4*)(vp + 24);
    }

    f32x16 s0, s1;
    #pragma unroll
    for (int i = 0; i < 16; i++) { s0[i] = 0.f; s1[i] = 0.f; }
    #pragma unroll
    for (int ks = 0; ks < 8; ks++) {
      f16x8 a0 = *(const f16x8*)&Ks[cur][cc][ks * 16 + hi * 8];
      f16x8 a1 = *(const f16x8*)&Ks[cur][32 + cc][ks * 16 + hi * 8];
      s0 = mfma32(a0, qf[ks], s0);
      s1 = mfma32(a1, qf[ks], s1);
    }
    // tree-reduce row max (lane cc owns q-row cc; partner lane^32 has other keys)
    float t[16];
    #pragma unroll
    for (int i = 0; i < 16; i++) t[i] = fmaxf(s0[i], s1[i]);
    #pragma unroll
    for (int st = 8; st >= 1; st >>= 1)
      #pragma unroll
      for (int i = 0; i < st; i++) t[i] = fmaxf(t[i], t[i + st]);
    const float pmax = fmaxf(t[0], __shfl_xor(t[0], 32));

    if (__all(pmax <= m)) {
      // max unchanged -> alpha == 1 exactly; skip rescale
      float rs = 0.f;
      #pragma unroll
      for (int i = 0; i < 16; i++) { float e = __expf(s0[i] - m); s0[i] = e; rs += e; }
      #pragma unroll
      for (int i = 0; i < 16; i++) { float e = __expf(s1[i] - m); s1[i] = e; rs += e; }
      rs += __shfl_xor(rs, 32);
      l += rs;
    } else {
      const float mnew = fmaxf(m, pmax);
      const float alpha = __expf(m - mnew);
      float rs = 0.f;
      #pragma unroll
      for (int i = 0; i < 16; i++) { float e = __expf(s0[i] - mnew); s0[i] = e; rs += e; }
      #pragma unroll
      for (int i = 0; i < 16; i++) { float e = __expf(s1[i] - mnew); s1[i] = e; rs += e; }
      rs += __shfl_xor(rs, 32);
      l = l * alpha + rs;
      m = mnew;
      if (hi == 0) als[w][cc] = alpha;
      float ar[16];
      #pragma unroll
      for (int i = 0; i < 16; i++) ar[i] = als[w][(i & 3) + 8 * (i >> 2) + 4 * hi];
      #pragma unroll
      for (int nt = 0; nt < 4; nt++)
        #pragma unroll
        for (int i = 0; i < 16; i++) o[nt][i] *= ar[i];
    }

    // in-register P -> A-fragments: pack pairs, swap halves across lane^32.
    f16x8 pav[4];
    {
      unsigned Wt[8];
      #pragma unroll
      for (int t2 = 0; t2 < 8; t2++) Wt[t2] = pkrtz(s0[2 * t2], s0[2 * t2 + 1]);
      asm volatile("v_permlane32_swap_b32 %0, %1" : "+v"(Wt[0]), "+v"(Wt[2]));
      asm volatile("v_permlane32_swap_b32 %0, %1" : "+v"(Wt[1]), "+v"(Wt[3]));
      asm volatile("v_permlane32_swap_b32 %0, %1" : "+v"(Wt[4]), "+v"(Wt[6]));
      asm volatile("v_permlane32_swap_b32 %0, %1" : "+v"(Wt[5]), "+v"(Wt[7]));
      union { unsigned u[4]; f16x8 v; } u0, u1;
      #pragma unroll
      for (int t2 = 0; t2 < 4; t2++) { u0.u[t2] = Wt[t2]; u1.u[t2] = Wt[4 + t2]; }
      pav[0] = u0.v; pav[1] = u1.v;
      #pragma unroll
      for (int t2 = 0; t2 < 8; t2++) Wt[t2] = pkrtz(s1[2 * t2], s1[2 * t2 + 1]);
      asm volatile("v_permlane32_swap_b32 %0, %1" : "+v"(Wt[0]), "+v"(Wt[2]));
      asm volatile("v_permlane32_swap_b32 %0, %1" : "+v"(Wt[1]), "+v"(Wt[3]));
      asm volatile("v_permlane32_swap_b32 %0, %1" : "+v"(Wt[4]), "+v"(Wt[6]));
      asm volatile("v_permlane32_swap_b32 %0, %1" : "+v"(Wt[5]), "+v"(Wt[7]));
      #pragma unroll
      for (int t2 = 0; t2 < 4; t2++) { u0.u[t2] = Wt[t2]; u1.u[t2] = Wt[4 + t2]; }
      pav[2] = u0.v; pav[3] = u1.v;
    }

    #pragma unroll
    for (int ks = 0; ks < 4; ks++) {
      #pragma unroll
      for (int nt = 0; nt < 4; nt++) {
        f16x8 bv = *(const f16x8*)&Vs[cur][nt * 32 + cc][ks * 16 + hi * 8];
        o[nt] = mfma32(pav[ks], bv, o[nt]);
      }
    }

    // write prefetched tile into the other buffer (prev iter's barrier made it dead)
    if (pf) {
      const int nxt = cur ^ 1;
      *(int4*)&Ks[nxt][kkey][kcb]      = kr0;
      *(int4*)&Ks[nxt][kkey][kcb + 8]  = kr1;
      *(int4*)&Ks[nxt][kkey][kcb + 16] = kr2;
      *(int4*)&Ks[nxt][kkey][kcb + 24] = kr3;
      *(int4*)&Vs[nxt][vd][vh]      = vr0;
      *(int4*)&Vs[nxt][vd][vh + 8]  = vr1;
      *(int4*)&Vs[nxt][vd][vh + 16] = vr2;
      *(int4*)&Vs[nxt][vd][vh + 24] = vr3;
    }
    __syncthreads();
  }
  // epilogue: raw partial O + (m,l)
  const size_t obase = (((size_t)kh * NBAT + b) * NTOK + qt * 128 + w * 32);
  if (hi == 0) {
    const size_t mi = obase + cc;
    ML[mi * 2] = m; ML[mi * 2 + 1] = l;
  }
  #pragma unroll
  for (int nt = 0; nt < 4; nt++)
    #pragma unroll
    for (int i = 0; i < 16; i++) {
      int row = (i & 3) + 8 * (i >> 2) + 4 * hi;
      OP[(obase + row) * NCS + nt * 32 + cc] = f2h(o[nt][i]);
    }
}

// ---------------- 4: combine the key-split partials ----------------
template <int S>
__global__ void k_comb(const f16* __restrict__ OP, const float* __restrict__ ML,
                       f16* __restrict__ Oa) {
  const int gid = blockIdx.x * 256 + threadIdx.x;   // 262144 = 16384 tok x 16 dgroups
  const int tok = gid >> 4, dg = (gid & 15) * 8;
  const int b = tok >> 12, tn = tok & 4095;
  float mv[S], lv[S];
  float mm = -1e30f;
  #pragma unroll
  for (int s = 0; s < S; s++) {
    const size_t idx = (((size_t)s * NBAT + b) * NTOK + tn);
    mv[s] = ML[idx * 2]; lv[s] = ML[idx * 2 + 1];
    mm = fmaxf(mm, mv[s]);
  }
  float den = 0.f, wsc[S];
  #pragma unroll
  for (int s = 0; s < S; s++) { wsc[s] = __expf(mv[s] - mm); den += wsc[s] * lv[s]; }
  const float inv = 1.f / den;
  float oacc[8];
  #pragma unroll
  for (int j = 0; j < 8; j++) oacc[j] = 0.f;
  #pragma unroll
  for (int s = 0; s < S; s++) {
    const size_t idx = (((size_t)s * NBAT + b) * NTOK + tn);
    int4 v = *(const int4*)(OP + idx * NCS + dg);
    const f16* a = (const f16*)&v;
    #pragma unroll
    for (int j = 0; j < 8; j++) oacc[j] += wsc[s] * h2f(a[j]);
  }
  f16x8 vv;
  #pragma unroll
  for (int j = 0; j < 8; j++) vv[j] = f2h(oacc[j] * inv);
  *(f16x8*)(Oa + ((size_t)b * NTOK + tn) * NCS + dg) = vv;
}

// ---------------- 5: output conv + BN partial sums + transpose-store ----------------
__launch_bounds__(256)
__global__ void k_out(const f16* __restrict__ Oa, const f16* __restrict__ wob,
                      const float* __restrict__ bo,
                      f16* __restrict__ Yb, float* __restrict__ Psum) {
  __shared__ f16 Es[256][72];   // [co][tok], +8 pad
  const int tid = threadIdx.x;
  const int b = blockIdx.y, tt = blockIdx.x, t0 = tt * 64;
  const int lane = tid & 63, w = tid >> 6, cc = lane & 31, hi = lane >> 5;
  const int th = w >> 1, oh = w & 1;
  const f16* op = Oa + ((size_t)b * NTOK + t0 + th * 32 + cc) * NCS + hi * 8;
  f16x8 af[8];
  #pragma unroll
  for (int ks = 0; ks < 8; ks++) af[ks] = *(const f16x8*)(op + ks * 16);
  f32x16 acc[4];
  #pragma unroll
  for (int nt = 0; nt < 4; nt++)
    #pragma unroll
    for (int i = 0; i < 16; i++) acc[nt][i] = 0.f;
  #pragma unroll
  for (int ks = 0; ks < 8; ks++)
    #pragma unroll
    for (int nt = 0; nt < 4; nt++) {
      f16x8 bw = *(const f16x8*)(wob + (size_t)(oh * 128 + nt * 32 + cc) * NCS + ks * 16 + hi * 8);
      acc[nt] = mfma32(af[ks], bw, acc[nt]);
    }
  #pragma unroll
  for (int nt = 0; nt < 4; nt++) {
    const int co = oh * 128 + nt * 32 + cc;
    const float bias = bo[co];
    float s = 0.f, sq = 0.f;
    #pragma unroll
    for (int i = 0; i < 16; i++) {
      float v = acc[nt][i] + bias;
      acc[nt][i] = v; s += v; sq += v * v;
    }
    s += __shfl_xor(s, 32); sq += __shfl_xor(sq, 32);
    if (hi == 0) {
      const size_t pi = ((size_t)(b * 64 + tt) * 2 + th) * NCH + co;
      Psum[pi * 2] = s; Psum[pi * 2 + 1] = sq;
    }
    #pragma unroll
    for (int q = 0; q < 4; q++) {
      f16x4 pk;
      #pragma unroll
      for (int j = 0; j < 4; j++) pk[j] = f2h(acc[nt][4 * q + j]);
      *(f16x4*)&Es[co][th * 32 + q * 8 + hi * 4] = pk;
    }
  }
  __syncthreads();
  {
    const f16* er = &Es[tid][0];
    f16* yp = Yb + ((size_t)b * NCH + tid) * NTOK + t0;
    #pragma unroll
    for (int p = 0; p < 8; p++)
      *(int4*)(yp + p * 8) = *(const int4*)(er + p * 8);
  }
}

// ---------------- 6: BN stats ----------------
__global__ void k_stats(const float* __restrict__ Psum, float* __restrict__ St) {
  const int ch = blockIdx.x, tid = threadIdx.x;
  float s = 0.f, sq = 0.f;
  for (int i = tid; i < 512; i += 128) {
    s  += Psum[((size_t)i * NCH + ch) * 2];
    sq += Psum[((size_t)i * NCH + ch) * 2 + 1];
  }
  #pragma unroll
  for (int off = 32; off >= 1; off >>= 1) { s += __shfl_down(s, off); sq += __shfl_down(sq, off); }
  __shared__ float red[4];
  if ((tid & 63) == 0) { red[(tid >> 6) * 2] = s; red[(tid >> 6) * 2 + 1] = sq; }
  __syncthreads();
  if (tid == 0) {
    s = red[0] + red[2]; sq = red[1] + red[3];
    const float mean = s * (1.f / 16384.f);
    const float var = sq * (1.f / 16384.f) - mean * mean;
    St[ch * 2] = mean;
    St[ch * 2 + 1] = 1.f / sqrtf(var + 1e-5f);
  }
}

// ---------------- 7: BN apply + ReLU + residual ----------------
__global__ void k_final(const f16* __restrict__ Yb, const float* __restrict__ x,
                        const float* __restrict__ St, const float* __restrict__ gamma,
                        const float* __restrict__ beta, float* __restrict__ out) {
  const size_t i = ((size_t)blockIdx.x * 256 + threadIdx.x) * 8;
  const int ch = (int)((i >> 12) & 255);
  const float mean = St[ch * 2], rstd = St[ch * 2 + 1];
  const float sc = gamma[ch] * rstd;
  const float sh = beta[ch] - mean * sc;
  int4 yv = *(const int4*)(Yb + i);
  const f16* ys = (const f16*)&yv;
  const float4 x0 = *(const float4*)(x + i);
  const float4 x1 = *(const float4*)(x + i + 4);
  float4 o0, o1;
  o0.x = fmaxf(h2f(ys[0]) * sc + sh, 0.f) + x0.x;
  o0.y = fmaxf(h2f(ys[1]) * sc + sh, 0.f) + x0.y;
  o0.z = fmaxf(h2f(ys[2]) * sc + sh, 0.f) + x0.z;
  o0.w = fmaxf(h2f(ys[3]) * sc + sh, 0.f) + x0.w;
  o1.x = fmaxf(h2f(ys[4]) * sc + sh, 0.f) + x1.x;
  o1.y = fmaxf(h2f(ys[5]) * sc + sh, 0.f) + x1.y;
  o1.z = fmaxf(h2f(ys[6]) * sc + sh, 0.f) + x1.z;
  o1.w = fmaxf(h2f(ys[7]) * sc + sh, 0.f) + x1.w;
  *(float4*)(out + i) = o0;
  *(float4*)(out + i + 4) = o1;
}

extern "C" void kernel_launch(void* const* d_in, const int* in_sizes, int n_in,
                              void* d_out, int out_size, void* d_ws, size_t ws_size,
                              hipStream_t stream) {
  const float* x     = (const float*)d_in[0];
  const float* Wq    = (const float*)d_in[1];
  const float* bq    = (const float*)d_in[2];
  const float* Wk    = (const float*)d_in[3];
  const float* bk    = (const float*)d_in[4];
  const float* Wv    = (const float*)d_in[5];
  const float* bv    = (const float*)d_in[6];
  const float* Wo    = (const float*)d_in[7];
  const float* bo    = (const float*)d_in[8];
  const float* gamma = (const float*)d_in[9];
  const float* beta  = (const float*)d_in[10];
  float* out = (float*)d_out;
  char* ws = (char*)d_ws;

  // ---- workspace layout with liveness-based aliasing ----
  const size_t OFF_W  = 0;                      // 4 x 65536 B weight f16
  const size_t OFF_QT = 262144;
  const size_t OFF_KT = OFF_QT + 4194304;
  const size_t OFF_VC = OFF_KT + 4194304;
  const size_t OFF_OP = OFF_VC + 4194304;       // 12,845,056
  const size_t opsz8 = (size_t)8 * NBAT * NTOK * NCS * 2;   // 33.5 MB
  const size_t mlsz8 = (size_t)8 * NBAT * NTOK * 2 * 4;
  const size_t need8 = OFF_OP + opsz8 + mlsz8 + 1048576 + 4096;
  const int SPLIT = (ws_size >= need8) ? 8 : 4;
  const size_t opsz = (size_t)SPLIT * NBAT * NTOK * NCS * 2;
  const size_t mlsz = (size_t)SPLIT * NBAT * NTOK * 2 * 4;
  const size_t OFF_ML = OFF_OP + opsz;
  const size_t OFF_PS = OFF_ML + mlsz;
  const size_t OFF_ST = OFF_PS + 1048576;

  f16* wqb = (f16*)(ws + OFF_W);
  f16* wkb = (f16*)(ws + OFF_W + 65536);
  f16* wvb = (f16*)(ws + OFF_W + 131072);
  f16* wob = (f16*)(ws + OFF_W + 196608);
  f16* Qt  = (f16*)(ws + OFF_QT);
  f16* Kt  = (f16*)(ws + OFF_KT);
  f16* Vc  = (f16*)(ws + OFF_VC);
  f16* OP  = (f16*)(ws + OFF_OP);
  float* ML = (float*)(ws + OFF_ML);
  float* Psum = (float*)(ws + OFF_PS);
  float* St   = (float*)(ws + OFF_ST);
  f16* Yb = (f16*)(ws + OFF_QT);   // alias: Qt+Kt dead after k_attn
  f16* Oa = (f16*)(ws + OFF_VC);   // alias: Vc dead after k_attn

  k_wconv<<<512, 256, 0, stream>>>(Wq, Wk, Wv, Wo, wqb);
  k_qkv<<<dim3(128, 4), 768, 0, stream>>>(x, wqb, wkb, wvb, bq, bk, bv, Qt, Kt, Vc);
  k_attn<<<dim3(4 * SPLIT, 32), 256, 0, stream>>>(Qt, Kt, Vc, OP, ML, 64 / SPLIT);
  if (SPLIT == 8) k_comb<8><<<1024, 256, 0, stream>>>(OP, ML, Oa);
  else            k_comb<4><<<1024, 256, 0, stream>>>(OP, ML, Oa);
  k_out<<<dim3(64, 4), 256, 0, stream>>>(Oa, wob, bo, Yb, Psum);
  k_stats<<<256, 128, 0, stream>>>(Psum, St);
  k_final<<<2048, 256, 0, stream>>>(Yb, x, St, gamma, beta, out);
}

// Round 12
// 199.532 us; speedup vs baseline: 1.0602x; 1.0602x over previous
//
#include <hip/hip_runtime.h>

#define NTOK 4096
#define NCH  256
#define NCS  128
#define NBAT 4

typedef _Float16 f16;
typedef _Float16 f16x8 __attribute__((ext_vector_type(8)));
typedef _Float16 f16x4 __attribute__((ext_vector_type(4)));
typedef __fp16 fp16x2 __attribute__((ext_vector_type(2)));
typedef float f32x16 __attribute__((ext_vector_type(16)));

__device__ __forceinline__ f16 f2h(float f) { return (f16)f; }
__device__ __forceinline__ float h2f(f16 h) { return (float)h; }
__device__ __forceinline__ unsigned short h2s(f16 h) {
  union { f16 h; unsigned short s; } u; u.h = h; return u.s;
}
__device__ __forceinline__ f32x16 mfma32(f16x8 a, f16x8 b, f32x16 c) {
  return __builtin_amdgcn_mfma_f32_32x32x16_f16(a, b, c, 0, 0, 0);
}
__device__ __forceinline__ unsigned pkrtz(float a, float b) {
  union { fp16x2 h; unsigned u; } u;
  u.h = __builtin_amdgcn_cvt_pkrtz(a, b);
  return u.u;
}

// ---------------- 1: weights -> f16 ----------------
__global__ void k_wconv(const float* __restrict__ wq, const float* __restrict__ wk,
                        const float* __restrict__ wv, const float* __restrict__ wo,
                        f16* __restrict__ out) {
  int i = blockIdx.x * 256 + threadIdx.x;   // 131072 total
  int seg = i >> 15, off = i & 32767;
  const float* s = (seg == 0) ? wq : (seg == 1) ? wk : (seg == 2) ? wv : wo;
  out[i] = f2h(s[off]);
}

// ---------------- 2: fused QKV projection (MFMA), 12 waves/block ----------------
// grid (128, 4): 32-token tiles. wave w -> proj p=w>>2 (Q,K,V), out-ch tile nt=w&3.
__launch_bounds__(768)
__global__ void k_qkv(const float* __restrict__ x,
                      const f16* __restrict__ wqb, const f16* __restrict__ wkb,
                      const f16* __restrict__ wvb,
                      const float* __restrict__ bq, const float* __restrict__ bk,
                      const float* __restrict__ bv,
                      f16* __restrict__ Qt, f16* __restrict__ Kt, f16* __restrict__ Vc) {
  __shared__ f16 Xs[32][264];   // [token][c], +8 pad
  const int tid = threadIdx.x;
  const int b = blockIdx.y;
  const int t0 = blockIdx.x * 32;
  // stage X tile: 32 tok x 128 channel-pairs
  for (int idx = tid; idx < 4096; idx += 768) {
    const int tok = idx & 31, cp = idx >> 5;
    const float* xp = x + ((size_t)(b * NCH + 2 * cp)) * NTOK + t0 + tok;
    float f0 = xp[0];
    float f1 = xp[NTOK];
    unsigned pk = (unsigned)h2s(f2h(f0)) | ((unsigned)h2s(f2h(f1)) << 16);
    *(unsigned*)&Xs[tok][2 * cp] = pk;
  }
  __syncthreads();
  const int lane = tid & 63, w = tid >> 6;
  const int p = w >> 2, nt = w & 3;
  const int cc = lane & 31, hi = lane >> 5;
  const f16* wb = (p == 0) ? wqb : (p == 1) ? wkb : wvb;
  const float* bp = (p == 0) ? bq : (p == 1) ? bk : bv;

  f32x16 acc;
  #pragma unroll
  for (int i = 0; i < 16; i++) acc[i] = 0.f;
  #pragma unroll
  for (int ks = 0; ks < 16; ks++) {
    f16x8 a = *(const f16x8*)&Xs[cc][ks * 16 + hi * 8];
    f16x8 bw = *(const f16x8*)(wb + (size_t)(nt * 32 + cc) * NCH + ks * 16 + hi * 8);
    acc = mfma32(a, bw, acc);
  }
  const int oc = nt * 32 + cc;
  const float bias = bp[oc];
  if (p < 2) {   // Q,K token-major [B][N][128]
    f16* dst = (p == 0) ? Qt : Kt;
    #pragma unroll
    for (int i = 0; i < 16; i++) {
      int row = (i & 3) + 8 * (i >> 2) + 4 * hi;
      dst[((size_t)b * NTOK + t0 + row) * NCS + oc] = f2h(acc[i] + bias);
    }
  } else {       // V channel-major [B][128][N]
    #pragma unroll
    for (int q = 0; q < 4; q++) {
      f16x4 pk;
      #pragma unroll
      for (int j = 0; j < 4; j++) pk[j] = f2h(acc[4 * q + j] + bias);
      *(f16x4*)(Vc + ((size_t)b * NCS + oc) * NTOK + t0 + 8 * q + 4 * hi) = pk;
    }
  }
}

// ---------------- 3: flash attention, key-split 4 ways, 4 waves/block ----------------
// r10 configuration (best measured: 87us): LDS double-buffer, one barrier/iter,
// launch_bounds(256,2) — arch regs capped 128, modest latency-hidden spill, 2 waves/SIMD.
// SPLIT=4: 512 blocks = exactly 2/CU, OP/ML traffic halved vs SPLIT=8.
__launch_bounds__(256, 2)
__global__ void k_attn(const f16* __restrict__ Qt, const f16* __restrict__ Kt,
                       const f16* __restrict__ Vc,
                       f16* __restrict__ OP, float* __restrict__ ML, int niter) {
  __shared__ f16 Ks[2][64][136];    // [buf][key][c], +8 pad
  __shared__ f16 Vs[2][128][72];    // [buf][d][key], +8 pad (V^T)
  __shared__ float als[4][32];
  const int tid = threadIdx.x;
  const int b = blockIdx.x & 3, kh = blockIdx.x >> 2, qt = blockIdx.y;
  const int lane = tid & 63, w = tid >> 6, cc = lane & 31, hi = lane >> 5;

  const f16* qp = Qt + ((size_t)b * NTOK + qt * 128 + w * 32 + cc) * NCS + hi * 8;
  f16x8 qf[8];
  #pragma unroll
  for (int ks = 0; ks < 8; ks++) qf[ks] = *(const f16x8*)(qp + ks * 16);

  f32x16 o[4];
  #pragma unroll
  for (int nt = 0; nt < 4; nt++)
    #pragma unroll
    for (int i = 0; i < 16; i++) o[nt][i] = 0.f;
  float m = -1e30f, l = 0.f;

  const int kkey = tid >> 2, kcb = (tid & 3) * 32;   // K staging map (256 thr)
  const int vd = tid >> 1, vh = (tid & 1) * 32;      // V staging map
  const int kb0 = kh * niter * 64;
  const f16* kbase = Kt + ((size_t)b * NTOK + kkey) * NCS + kcb;
  const f16* vbase = Vc + ((size_t)b * NCS + vd) * NTOK + vh;

  // prologue: stage tile 0 into buffer 0
  {
    const f16* kp = kbase + (size_t)kb0 * NCS;
    const f16* vp = vbase + kb0;
    #pragma unroll
    for (int pp = 0; pp < 4; pp++) {
      *(int4*)&Ks[0][kkey][kcb + pp * 8] = *(const int4*)(kp + pp * 8);
      *(int4*)&Vs[0][vd][vh + pp * 8] = *(const int4*)(vp + pp * 8);
    }
  }
  __syncthreads();

  for (int it = 0; it < niter; it++) {
    const int cur = it & 1;
    // issue next-tile loads NOW; they complete during compute below
    int4 kr0, kr1, kr2, kr3, vr0, vr1, vr2, vr3;
    const bool pf = (it + 1 < niter);
    if (pf) {
      const int kb = kb0 + (it + 1) * 64;
      const f16* kp = kbase + (size_t)kb * NCS;
      const f16* vp = vbase + kb;
      kr0 = *(const int4*)(kp);      kr1 = *(const int4*)(kp + 8);
      kr2 = *(const int4*)(kp + 16); kr3 = *(const int4*)(kp + 24);
      vr0 = *(const int4*)(vp);      vr1 = *(const int4*)(vp + 8);
      vr2 = *(const int4*)(vp + 16); vr3 = *(const int4*)(vp + 24);
    }

    f32x16 s0, s1;
    #pragma unroll
    for (int i = 0; i < 16; i++) { s0[i] = 0.f; s1[i] = 0.f; }
    #pragma unroll
    for (int ks = 0; ks < 8; ks++) {
      f16x8 a0 = *(const f16x8*)&Ks[cur][cc][ks * 16 + hi * 8];
      f16x8 a1 = *(const f16x8*)&Ks[cur][32 + cc][ks * 16 + hi * 8];
      s0 = mfma32(a0, qf[ks], s0);
      s1 = mfma32(a1, qf[ks], s1);
    }
    // tree-reduce row max (lane cc owns q-row cc; partner lane^32 has other keys)
    float t[16];
    #pragma unroll
    for (int i = 0; i < 16; i++) t[i] = fmaxf(s0[i], s1[i]);
    #pragma unroll
    for (int st = 8; st >= 1; st >>= 1)
      #pragma unroll
      for (int i = 0; i < st; i++) t[i] = fmaxf(t[i], t[i + st]);
    const float pmax = fmaxf(t[0], __shfl_xor(t[0], 32));

    if (__all(pmax <= m)) {
      // max unchanged -> alpha == 1 exactly; skip rescale
      float rs = 0.f;
      #pragma unroll
      for (int i = 0; i < 16; i++) { float e = __expf(s0[i] - m); s0[i] = e; rs += e; }
      #pragma unroll
      for (int i = 0; i < 16; i++) { float e = __expf(s1[i] - m); s1[i] = e; rs += e; }
      rs += __shfl_xor(rs, 32);
      l += rs;
    } else {
      const float mnew = fmaxf(m, pmax);
      const float alpha = __expf(m - mnew);
      float rs = 0.f;
      #pragma unroll
      for (int i = 0; i < 16; i++) { float e = __expf(s0[i] - mnew); s0[i] = e; rs += e; }
      #pragma unroll
      for (int i = 0; i < 16; i++) { float e = __expf(s1[i] - mnew); s1[i] = e; rs += e; }
      rs += __shfl_xor(rs, 32);
      l = l * alpha + rs;
      m = mnew;
      if (hi == 0) als[w][cc] = alpha;
      float ar[16];
      #pragma unroll
      for (int i = 0; i < 16; i++) ar[i] = als[w][(i & 3) + 8 * (i >> 2) + 4 * hi];
      #pragma unroll
      for (int nt = 0; nt < 4; nt++)
        #pragma unroll
        for (int i = 0; i < 16; i++) o[nt][i] *= ar[i];
    }

    // in-register P -> A-fragments: pack pairs, swap halves across lane^32.
    f16x8 pav[4];
    {
      unsigned Wt[8];
      #pragma unroll
      for (int t2 = 0; t2 < 8; t2++) Wt[t2] = pkrtz(s0[2 * t2], s0[2 * t2 + 1]);
      asm volatile("v_permlane32_swap_b32 %0, %1" : "+v"(Wt[0]), "+v"(Wt[2]));
      asm volatile("v_permlane32_swap_b32 %0, %1" : "+v"(Wt[1]), "+v"(Wt[3]));
      asm volatile("v_permlane32_swap_b32 %0, %1" : "+v"(Wt[4]), "+v"(Wt[6]));
      asm volatile("v_permlane32_swap_b32 %0, %1" : "+v"(Wt[5]), "+v"(Wt[7]));
      union { unsigned u[4]; f16x8 v; } u0, u1;
      #pragma unroll
      for (int t2 = 0; t2 < 4; t2++) { u0.u[t2] = Wt[t2]; u1.u[t2] = Wt[4 + t2]; }
      pav[0] = u0.v; pav[1] = u1.v;
      #pragma unroll
      for (int t2 = 0; t2 < 8; t2++) Wt[t2] = pkrtz(s1[2 * t2], s1[2 * t2 + 1]);
      asm volatile("v_permlane32_swap_b32 %0, %1" : "+v"(Wt[0]), "+v"(Wt[2]));
      asm volatile("v_permlane32_swap_b32 %0, %1" : "+v"(Wt[1]), "+v"(Wt[3]));
      asm volatile("v_permlane32_swap_b32 %0, %1" : "+v"(Wt[4]), "+v"(Wt[6]));
      asm volatile("v_permlane32_swap_b32 %0, %1" : "+v"(Wt[5]), "+v"(Wt[7]));
      #pragma unroll
      for (int t2 = 0; t2 < 4; t2++) { u0.u[t2] = Wt[t2]; u1.u[t2] = Wt[4 + t2]; }
      pav[2] = u0.v; pav[3] = u1.v;
    }

    #pragma unroll
    for (int ks = 0; ks < 4; ks++) {
      #pragma unroll
      for (int nt = 0; nt < 4; nt++) {
        f16x8 bv = *(const f16x8*)&Vs[cur][nt * 32 + cc][ks * 16 + hi * 8];
        o[nt] = mfma32(pav[ks], bv, o[nt]);
      }
    }

    // write prefetched tile into the other buffer (prev iter's barrier made it dead)
    if (pf) {
      const int nxt = cur ^ 1;
      *(int4*)&Ks[nxt][kkey][kcb]      = kr0;
      *(int4*)&Ks[nxt][kkey][kcb + 8]  = kr1;
      *(int4*)&Ks[nxt][kkey][kcb + 16] = kr2;
      *(int4*)&Ks[nxt][kkey][kcb + 24] = kr3;
      *(int4*)&Vs[nxt][vd][vh]      = vr0;
      *(int4*)&Vs[nxt][vd][vh + 8]  = vr1;
      *(int4*)&Vs[nxt][vd][vh + 16] = vr2;
      *(int4*)&Vs[nxt][vd][vh + 24] = vr3;
    }
    __syncthreads();
  }
  // epilogue: raw partial O + (m,l)
  const size_t obase = (((size_t)kh * NBAT + b) * NTOK + qt * 128 + w * 32);
  if (hi == 0) {
    const size_t mi = obase + cc;
    ML[mi * 2] = m; ML[mi * 2 + 1] = l;
  }
  #pragma unroll
  for (int nt = 0; nt < 4; nt++)
    #pragma unroll
    for (int i = 0; i < 16; i++) {
      int row = (i & 3) + 8 * (i >> 2) + 4 * hi;
      OP[(obase + row) * NCS + nt * 32 + cc] = f2h(o[nt][i]);
    }
}

// ---------------- 4: output conv (fused key-split combine) + BN partials + transpose ----------------
__launch_bounds__(256)
__global__ void k_out(const f16* __restrict__ OP, const float* __restrict__ ML,
                      const f16* __restrict__ wob, const float* __restrict__ bo,
                      f16* __restrict__ Yb, float* __restrict__ Psum) {
  __shared__ f16 Es[256][72];   // [co][tok], +8 pad
  const int tid = threadIdx.x;
  const int b = blockIdx.y, tt = blockIdx.x, t0 = tt * 64;
  const int lane = tid & 63, w = tid >> 6, cc = lane & 31, hi = lane >> 5;
  const int th = w >> 1, oh = w & 1;
  const int tok = t0 + th * 32 + cc;

  // combine weights for this token (4 key-splits)
  float mv[4], lv[4], mm = -1e30f;
  #pragma unroll
  for (int s = 0; s < 4; s++) {
    const size_t idx = ((size_t)(s * NBAT + b) * NTOK + tok);
    mv[s] = ML[idx * 2]; lv[s] = ML[idx * 2 + 1];
    mm = fmaxf(mm, mv[s]);
  }
  float den = 0.f, wsc[4];
  #pragma unroll
  for (int s = 0; s < 4; s++) { wsc[s] = __expf(mv[s] - mm); den += wsc[s] * lv[s]; }
  const float inv = 1.f / den;

  f16x8 af[8];
  #pragma unroll
  for (int ks = 0; ks < 8; ks++) {
    float oacc[8];
    #pragma unroll
    for (int j = 0; j < 8; j++) oacc[j] = 0.f;
    #pragma unroll
    for (int s = 0; s < 4; s++) {
      int4 v = *(const int4*)(OP + ((size_t)(s * NBAT + b) * NTOK + tok) * NCS + ks * 16 + hi * 8);
      const f16* a = (const f16*)&v;
      #pragma unroll
      for (int j = 0; j < 8; j++) oacc[j] += wsc[s] * h2f(a[j]);
    }
    #pragma unroll
    for (int j = 0; j < 8; j++) af[ks][j] = f2h(oacc[j] * inv);
  }

  f32x16 acc[4];
  #pragma unroll
  for (int nt = 0; nt < 4; nt++)
    #pragma unroll
    for (int i = 0; i < 16; i++) acc[nt][i] = 0.f;
  #pragma unroll
  for (int ks = 0; ks < 8; ks++)
    #pragma unroll
    for (int nt = 0; nt < 4; nt++) {
      f16x8 bw = *(const f16x8*)(wob + (size_t)(oh * 128 + nt * 32 + cc) * NCS + ks * 16 + hi * 8);
      acc[nt] = mfma32(af[ks], bw, acc[nt]);
    }
  #pragma unroll
  for (int nt = 0; nt < 4; nt++) {
    const int co = oh * 128 + nt * 32 + cc;
    const float bias = bo[co];
    float s = 0.f, sq = 0.f;
    #pragma unroll
    for (int i = 0; i < 16; i++) {
      float v = acc[nt][i] + bias;
      acc[nt][i] = v; s += v; sq += v * v;
    }
    s += __shfl_xor(s, 32); sq += __shfl_xor(sq, 32);
    if (hi == 0) {
      const size_t pi = ((size_t)(b * 64 + tt) * 2 + th) * NCH + co;
      Psum[pi * 2] = s; Psum[pi * 2 + 1] = sq;
    }
    #pragma unroll
    for (int q = 0; q < 4; q++) {
      f16x4 pk;
      #pragma unroll
      for (int j = 0; j < 4; j++) pk[j] = f2h(acc[nt][4 * q + j]);
      *(f16x4*)&Es[co][th * 32 + q * 8 + hi * 4] = pk;
    }
  }
  __syncthreads();
  {
    const f16* er = &Es[tid][0];
    f16* yp = Yb + ((size_t)b * NCH + tid) * NTOK + t0;
    #pragma unroll
    for (int p = 0; p < 8; p++)
      *(int4*)(yp + p * 8) = *(const int4*)(er + p * 8);
  }
}

// ---------------- 5: BN stats ----------------
__global__ void k_stats(const float* __restrict__ Psum, float* __restrict__ St) {
  const int ch = blockIdx.x, tid = threadIdx.x;
  float s = 0.f, sq = 0.f;
  for (int i = tid; i < 512; i += 128) {
    s  += Psum[((size_t)i * NCH + ch) * 2];
    sq += Psum[((size_t)i * NCH + ch) * 2 + 1];
  }
  #pragma unroll
  for (int off = 32; off >= 1; off >>= 1) { s += __shfl_down(s, off); sq += __shfl_down(sq, off); }
  __shared__ float red[4];
  if ((tid & 63) == 0) { red[(tid >> 6) * 2] = s; red[(tid >> 6) * 2 + 1] = sq; }
  __syncthreads();
  if (tid == 0) {
    s = red[0] + red[2]; sq = red[1] + red[3];
    const float mean = s * (1.f / 16384.f);
    const float var = sq * (1.f / 16384.f) - mean * mean;
    St[ch * 2] = mean;
    St[ch * 2 + 1] = 1.f / sqrtf(var + 1e-5f);
  }
}

// ---------------- 6: BN apply + ReLU + residual ----------------
__global__ void k_final(const f16* __restrict__ Yb, const float* __restrict__ x,
                        const float* __restrict__ St, const float* __restrict__ gamma,
                        const float* __restrict__ beta, float* __restrict__ out) {
  const size_t i = ((size_t)blockIdx.x * 256 + threadIdx.x) * 8;
  const int ch = (int)((i >> 12) & 255);
  const float mean = St[ch * 2], rstd = St[ch * 2 + 1];
  const float sc = gamma[ch] * rstd;
  const float sh = beta[ch] - mean * sc;
  int4 yv = *(const int4*)(Yb + i);
  const f16* ys = (const f16*)&yv;
  const float4 x0 = *(const float4*)(x + i);
  const float4 x1 = *(const float4*)(x + i + 4);
  float4 o0, o1;
  o0.x = fmaxf(h2f(ys[0]) * sc + sh, 0.f) + x0.x;
  o0.y = fmaxf(h2f(ys[1]) * sc + sh, 0.f) + x0.y;
  o0.z = fmaxf(h2f(ys[2]) * sc + sh, 0.f) + x0.z;
  o0.w = fmaxf(h2f(ys[3]) * sc + sh, 0.f) + x0.w;
  o1.x = fmaxf(h2f(ys[4]) * sc + sh, 0.f) + x1.x;
  o1.y = fmaxf(h2f(ys[5]) * sc + sh, 0.f) + x1.y;
  o1.z = fmaxf(h2f(ys[6]) * sc + sh, 0.f) + x1.z;
  o1.w = fmaxf(h2f(ys[7]) * sc + sh, 0.f) + x1.w;
  *(float4*)(out + i) = o0;
  *(float4*)(out + i + 4) = o1;
}

extern "C" void kernel_launch(void* const* d_in, const int* in_sizes, int n_in,
                              void* d_out, int out_size, void* d_ws, size_t ws_size,
                              hipStream_t stream) {
  const float* x     = (const float*)d_in[0];
  const float* Wq    = (const float*)d_in[1];
  const float* bq    = (const float*)d_in[2];
  const float* Wk    = (const float*)d_in[3];
  const float* bk    = (const float*)d_in[4];
  const float* Wv    = (const float*)d_in[5];
  const float* bv    = (const float*)d_in[6];
  const float* Wo    = (const float*)d_in[7];
  const float* bo    = (const float*)d_in[8];
  const float* gamma = (const float*)d_in[9];
  const float* beta  = (const float*)d_in[10];
  float* out = (float*)d_out;
  char* ws = (char*)d_ws;

  // ---- workspace layout (SPLIT=4 fixed; total ~31.2 MB) ----
  const size_t OFF_W  = 0;                      // 4 x 65536 B weight f16
  const size_t OFF_QT = 262144;
  const size_t OFF_KT = OFF_QT + 4194304;
  const size_t OFF_VC = OFF_KT + 4194304;
  const size_t OFF_OP = OFF_VC + 4194304;       // 12,845,056
  const size_t opsz = (size_t)4 * NBAT * NTOK * NCS * 2;    // 16.78 MB
  const size_t mlsz = (size_t)4 * NBAT * NTOK * 2 * 4;      // 0.52 MB
  const size_t OFF_ML = OFF_OP + opsz;
  const size_t OFF_PS = OFF_ML + mlsz;
  const size_t OFF_ST = OFF_PS + 1048576;

  f16* wqb = (f16*)(ws + OFF_W);
  f16* wkb = (f16*)(ws + OFF_W + 65536);
  f16* wvb = (f16*)(ws + OFF_W + 131072);
  f16* wob = (f16*)(ws + OFF_W + 196608);
  f16* Qt  = (f16*)(ws + OFF_QT);
  f16* Kt  = (f16*)(ws + OFF_KT);
  f16* Vc  = (f16*)(ws + OFF_VC);
  f16* OP  = (f16*)(ws + OFF_OP);
  float* ML = (float*)(ws + OFF_ML);
  float* Psum = (float*)(ws + OFF_PS);
  float* St   = (float*)(ws + OFF_ST);
  f16* Yb = (f16*)(ws + OFF_QT);   // alias: Qt+Kt dead after k_attn

  k_wconv<<<512, 256, 0, stream>>>(Wq, Wk, Wv, Wo, wqb);
  k_qkv<<<dim3(128, 4), 768, 0, stream>>>(x, wqb, wkb, wvb, bq, bk, bv, Qt, Kt, Vc);
  k_attn<<<dim3(16, 32), 256, 0, stream>>>(Qt, Kt, Vc, OP, ML, 16);
  k_out<<<dim3(64, 4), 256, 0, stream>>>(OP, ML, wob, bo, Yb, Psum);
  k_stats<<<256, 128, 0, stream>>>(Psum, St);
  k_final<<<2048, 256, 0, stream>>>(Yb, x, St, gamma, beta, out);
}

// Round 13
// 196.476 us; speedup vs baseline: 1.0767x; 1.0156x over previous
//
#include <hip/hip_runtime.h>

#define NTOK 4096
#define NCH  256
#define NCS  128
#define NBAT 4

typedef _Float16 f16;
typedef _Float16 f16x8 __attribute__((ext_vector_type(8)));
typedef _Float16 f16x4 __attribute__((ext_vector_type(4)));
typedef __fp16 fp16x2 __attribute__((ext_vector_type(2)));
typedef float f32x16 __attribute__((ext_vector_type(16)));

__device__ __forceinline__ f16 f2h(float f) { return (f16)f; }
__device__ __forceinline__ float h2f(f16 h) { return (float)h; }
__device__ __forceinline__ unsigned short h2s(f16 h) {
  union { f16 h; unsigned short s; } u; u.h = h; return u.s;
}
__device__ __forceinline__ f32x16 mfma32(f16x8 a, f16x8 b, f32x16 c) {
  return __builtin_amdgcn_mfma_f32_32x32x16_f16(a, b, c, 0, 0, 0);
}
__device__ __forceinline__ unsigned pkrtz(float a, float b) {
  union { fp16x2 h; unsigned u; } u;
  u.h = __builtin_amdgcn_cvt_pkrtz(a, b);
  return u.u;
}

// ---------------- 1: weights -> f16 ----------------
__global__ void k_wconv(const float* __restrict__ wq, const float* __restrict__ wk,
                        const float* __restrict__ wv, const float* __restrict__ wo,
                        f16* __restrict__ out) {
  int i = blockIdx.x * 256 + threadIdx.x;   // 131072 total
  int seg = i >> 15, off = i & 32767;
  const float* s = (seg == 0) ? wq : (seg == 1) ? wk : (seg == 2) ? wv : wo;
  out[i] = f2h(s[off]);
}

// ---------------- 2: fused QKV projection (MFMA), 12 waves/block ----------------
// grid (128, 4): 32-token tiles. wave w -> proj p=w>>2 (Q,K,V), out-ch tile nt=w&3.
__launch_bounds__(768)
__global__ void k_qkv(const float* __restrict__ x,
                      const f16* __restrict__ wqb, const f16* __restrict__ wkb,
                      const f16* __restrict__ wvb,
                      const float* __restrict__ bq, const float* __restrict__ bk,
                      const float* __restrict__ bv,
                      f16* __restrict__ Qt, f16* __restrict__ Kt, f16* __restrict__ Vc) {
  __shared__ f16 Xs[32][264];   // [token][c], +8 pad
  const int tid = threadIdx.x;
  const int b = blockIdx.y;
  const int t0 = blockIdx.x * 32;
  // stage X tile: 32 tok x 128 channel-pairs
  for (int idx = tid; idx < 4096; idx += 768) {
    const int tok = idx & 31, cp = idx >> 5;
    const float* xp = x + ((size_t)(b * NCH + 2 * cp)) * NTOK + t0 + tok;
    float f0 = xp[0];
    float f1 = xp[NTOK];
    unsigned pk = (unsigned)h2s(f2h(f0)) | ((unsigned)h2s(f2h(f1)) << 16);
    *(unsigned*)&Xs[tok][2 * cp] = pk;
  }
  __syncthreads();
  const int lane = tid & 63, w = tid >> 6;
  const int p = w >> 2, nt = w & 3;
  const int cc = lane & 31, hi = lane >> 5;
  const f16* wb = (p == 0) ? wqb : (p == 1) ? wkb : wvb;
  const float* bp = (p == 0) ? bq : (p == 1) ? bk : bv;

  f32x16 acc;
  #pragma unroll
  for (int i = 0; i < 16; i++) acc[i] = 0.f;
  #pragma unroll
  for (int ks = 0; ks < 16; ks++) {
    f16x8 a = *(const f16x8*)&Xs[cc][ks * 16 + hi * 8];
    f16x8 bw = *(const f16x8*)(wb + (size_t)(nt * 32 + cc) * NCH + ks * 16 + hi * 8);
    acc = mfma32(a, bw, acc);
  }
  const int oc = nt * 32 + cc;
  const float bias = bp[oc];
  if (p < 2) {   // Q,K token-major [B][N][128]
    f16* dst = (p == 0) ? Qt : Kt;
    #pragma unroll
    for (int i = 0; i < 16; i++) {
      int row = (i & 3) + 8 * (i >> 2) + 4 * hi;
      dst[((size_t)b * NTOK + t0 + row) * NCS + oc] = f2h(acc[i] + bias);
    }
  } else {       // V channel-major [B][128][N]
    #pragma unroll
    for (int q = 0; q < 4; q++) {
      f16x4 pk;
      #pragma unroll
      for (int j = 0; j < 4; j++) pk[j] = f2h(acc[4 * q + j] + bias);
      *(f16x4*)(Vc + ((size_t)b * NCS + oc) * NTOK + t0 + 8 * q + 4 * hi) = pk;
    }
  }
}

// ---------------- 3: flash attention, key-split 4 ways, 4 waves/block ----------------
// r10/r12 configuration (best measured): LDS double-buffer, one barrier/iter,
// launch_bounds(256,2). UNCHANGED from round 12 for clean attribution.
__launch_bounds__(256, 2)
__global__ void k_attn(const f16* __restrict__ Qt, const f16* __restrict__ Kt,
                       const f16* __restrict__ Vc,
                       f16* __restrict__ OP, float* __restrict__ ML, int niter) {
  __shared__ f16 Ks[2][64][136];    // [buf][key][c], +8 pad
  __shared__ f16 Vs[2][128][72];    // [buf][d][key], +8 pad (V^T)
  __shared__ float als[4][32];
  const int tid = threadIdx.x;
  const int b = blockIdx.x & 3, kh = blockIdx.x >> 2, qt = blockIdx.y;
  const int lane = tid & 63, w = tid >> 6, cc = lane & 31, hi = lane >> 5;

  const f16* qp = Qt + ((size_t)b * NTOK + qt * 128 + w * 32 + cc) * NCS + hi * 8;
  f16x8 qf[8];
  #pragma unroll
  for (int ks = 0; ks < 8; ks++) qf[ks] = *(const f16x8*)(qp + ks * 16);

  f32x16 o[4];
  #pragma unroll
  for (int nt = 0; nt < 4; nt++)
    #pragma unroll
    for (int i = 0; i < 16; i++) o[nt][i] = 0.f;
  float m = -1e30f, l = 0.f;

  const int kkey = tid >> 2, kcb = (tid & 3) * 32;   // K staging map (256 thr)
  const int vd = tid >> 1, vh = (tid & 1) * 32;      // V staging map
  const int kb0 = kh * niter * 64;
  const f16* kbase = Kt + ((size_t)b * NTOK + kkey) * NCS + kcb;
  const f16* vbase = Vc + ((size_t)b * NCS + vd) * NTOK + vh;

  // prologue: stage tile 0 into buffer 0
  {
    const f16* kp = kbase + (size_t)kb0 * NCS;
    const f16* vp = vbase + kb0;
    #pragma unroll
    for (int pp = 0; pp < 4; pp++) {
      *(int4*)&Ks[0][kkey][kcb + pp * 8] = *(const int4*)(kp + pp * 8);
      *(int4*)&Vs[0][vd][vh + pp * 8] = *(const int4*)(vp + pp * 8);
    }
  }
  __syncthreads();

  for (int it = 0; it < niter; it++) {
    const int cur = it & 1;
    // issue next-tile loads NOW; they complete during compute below
    int4 kr0, kr1, kr2, kr3, vr0, vr1, vr2, vr3;
    const bool pf = (it + 1 < niter);
    if (pf) {
      const int kb = kb0 + (it + 1) * 64;
      const f16* kp = kbase + (size_t)kb * NCS;
      const f16* vp = vbase + kb;
      kr0 = *(const int4*)(kp);      kr1 = *(const int4*)(kp + 8);
      kr2 = *(const int4*)(kp + 16); kr3 = *(const int4*)(kp + 24);
      vr0 = *(const int4*)(vp);      vr1 = *(const int4*)(vp + 8);
      vr2 = *(const int4*)(vp + 16); vr3 = *(const int4*)(vp + 24);
    }

    f32x16 s0, s1;
    #pragma unroll
    for (int i = 0; i < 16; i++) { s0[i] = 0.f; s1[i] = 0.f; }
    #pragma unroll
    for (int ks = 0; ks < 8; ks++) {
      f16x8 a0 = *(const f16x8*)&Ks[cur][cc][ks * 16 + hi * 8];
      f16x8 a1 = *(const f16x8*)&Ks[cur][32 + cc][ks * 16 + hi * 8];
      s0 = mfma32(a0, qf[ks], s0);
      s1 = mfma32(a1, qf[ks], s1);
    }
    // tree-reduce row max (lane cc owns q-row cc; partner lane^32 has other keys)
    float t[16];
    #pragma unroll
    for (int i = 0; i < 16; i++) t[i] = fmaxf(s0[i], s1[i]);
    #pragma unroll
    for (int st = 8; st >= 1; st >>= 1)
      #pragma unroll
      for (int i = 0; i < st; i++) t[i] = fmaxf(t[i], t[i + st]);
    const float pmax = fmaxf(t[0], __shfl_xor(t[0], 32));

    if (__all(pmax <= m)) {
      // max unchanged -> alpha == 1 exactly; skip rescale
      float rs = 0.f;
      #pragma unroll
      for (int i = 0; i < 16; i++) { float e = __expf(s0[i] - m); s0[i] = e; rs += e; }
      #pragma unroll
      for (int i = 0; i < 16; i++) { float e = __expf(s1[i] - m); s1[i] = e; rs += e; }
      rs += __shfl_xor(rs, 32);
      l += rs;
    } else {
      const float mnew = fmaxf(m, pmax);
      const float alpha = __expf(m - mnew);
      float rs = 0.f;
      #pragma unroll
      for (int i = 0; i < 16; i++) { float e = __expf(s0[i] - mnew); s0[i] = e; rs += e; }
      #pragma unroll
      for (int i = 0; i < 16; i++) { float e = __expf(s1[i] - mnew); s1[i] = e; rs += e; }
      rs += __shfl_xor(rs, 32);
      l = l * alpha + rs;
      m = mnew;
      if (hi == 0) als[w][cc] = alpha;
      float ar[16];
      #pragma unroll
      for (int i = 0; i < 16; i++) ar[i] = als[w][(i & 3) + 8 * (i >> 2) + 4 * hi];
      #pragma unroll
      for (int nt = 0; nt < 4; nt++)
        #pragma unroll
        for (int i = 0; i < 16; i++) o[nt][i] *= ar[i];
    }

    // in-register P -> A-fragments: pack pairs, swap halves across lane^32.
    f16x8 pav[4];
    {
      unsigned Wt[8];
      #pragma unroll
      for (int t2 = 0; t2 < 8; t2++) Wt[t2] = pkrtz(s0[2 * t2], s0[2 * t2 + 1]);
      asm volatile("v_permlane32_swap_b32 %0, %1" : "+v"(Wt[0]), "+v"(Wt[2]));
      asm volatile("v_permlane32_swap_b32 %0, %1" : "+v"(Wt[1]), "+v"(Wt[3]));
      asm volatile("v_permlane32_swap_b32 %0, %1" : "+v"(Wt[4]), "+v"(Wt[6]));
      asm volatile("v_permlane32_swap_b32 %0, %1" : "+v"(Wt[5]), "+v"(Wt[7]));
      union { unsigned u[4]; f16x8 v; } u0, u1;
      #pragma unroll
      for (int t2 = 0; t2 < 4; t2++) { u0.u[t2] = Wt[t2]; u1.u[t2] = Wt[4 + t2]; }
      pav[0] = u0.v; pav[1] = u1.v;
      #pragma unroll
      for (int t2 = 0; t2 < 8; t2++) Wt[t2] = pkrtz(s1[2 * t2], s1[2 * t2 + 1]);
      asm volatile("v_permlane32_swap_b32 %0, %1" : "+v"(Wt[0]), "+v"(Wt[2]));
      asm volatile("v_permlane32_swap_b32 %0, %1" : "+v"(Wt[1]), "+v"(Wt[3]));
      asm volatile("v_permlane32_swap_b32 %0, %1" : "+v"(Wt[4]), "+v"(Wt[6]));
      asm volatile("v_permlane32_swap_b32 %0, %1" : "+v"(Wt[5]), "+v"(Wt[7]));
      #pragma unroll
      for (int t2 = 0; t2 < 4; t2++) { u0.u[t2] = Wt[t2]; u1.u[t2] = Wt[4 + t2]; }
      pav[2] = u0.v; pav[3] = u1.v;
    }

    #pragma unroll
    for (int ks = 0; ks < 4; ks++) {
      #pragma unroll
      for (int nt = 0; nt < 4; nt++) {
        f16x8 bv = *(const f16x8*)&Vs[cur][nt * 32 + cc][ks * 16 + hi * 8];
        o[nt] = mfma32(pav[ks], bv, o[nt]);
      }
    }

    // write prefetched tile into the other buffer (prev iter's barrier made it dead)
    if (pf) {
      const int nxt = cur ^ 1;
      *(int4*)&Ks[nxt][kkey][kcb]      = kr0;
      *(int4*)&Ks[nxt][kkey][kcb + 8]  = kr1;
      *(int4*)&Ks[nxt][kkey][kcb + 16] = kr2;
      *(int4*)&Ks[nxt][kkey][kcb + 24] = kr3;
      *(int4*)&Vs[nxt][vd][vh]      = vr0;
      *(int4*)&Vs[nxt][vd][vh + 8]  = vr1;
      *(int4*)&Vs[nxt][vd][vh + 16] = vr2;
      *(int4*)&Vs[nxt][vd][vh + 24] = vr3;
    }
    __syncthreads();
  }
  // epilogue: raw partial O + (m,l)
  const size_t obase = (((size_t)kh * NBAT + b) * NTOK + qt * 128 + w * 32);
  if (hi == 0) {
    const size_t mi = obase + cc;
    ML[mi * 2] = m; ML[mi * 2 + 1] = l;
  }
  #pragma unroll
  for (int nt = 0; nt < 4; nt++)
    #pragma unroll
    for (int i = 0; i < 16; i++) {
      int row = (i & 3) + 8 * (i >> 2) + 4 * hi;
      OP[(obase + row) * NCS + nt * 32 + cc] = f2h(o[nt][i]);
    }
}

// ---------------- 4: output conv (fused combine, LDS-staged coalesced) ----------------
// Phase A: per-token combine weights -> wls; coalesced combine of 4 key-splits
// into Os tile (1 KB/wave contiguous segments). Phase B: MFMA from LDS fragments.
// Os aliases Es (union) behind a barrier -> LDS stays ~37 KB, 4 blocks/CU.
__launch_bounds__(256)
__global__ void k_out(const f16* __restrict__ OP, const float* __restrict__ ML,
                      const f16* __restrict__ wob, const float* __restrict__ bo,
                      f16* __restrict__ Yb, float* __restrict__ Psum) {
  __shared__ union {
    struct { f16 Os[64][136]; float wls[64][5]; } a;
    f16 Es[256][72];
  } sh;
  const int tid = threadIdx.x;
  const int b = blockIdx.y, tt = blockIdx.x, t0 = tt * 64;

  // phase A0: combine weights for the 64 tokens
  if (tid < 64) {
    const int tok = t0 + tid;
    float mv[4], lv[4], mm = -1e30f;
    #pragma unroll
    for (int s = 0; s < 4; s++) {
      const size_t idx = ((size_t)(s * NBAT + b) * NTOK + tok);
      mv[s] = ML[idx * 2]; lv[s] = ML[idx * 2 + 1];
      mm = fmaxf(mm, mv[s]);
    }
    float den = 0.f, wsc[4];
    #pragma unroll
    for (int s = 0; s < 4; s++) { wsc[s] = __expf(mv[s] - mm); den += wsc[s] * lv[s]; }
    #pragma unroll
    for (int s = 0; s < 4; s++) sh.a.wls[tid][s] = wsc[s];
    sh.a.wls[tid][4] = 1.f / den;
  }
  __syncthreads();

  // phase A1: coalesced combine (16 threads cover one token's 128 channels)
  #pragma unroll
  for (int k = 0; k < 4; k++) {
    const int c = tid + k * 256;          // 0..1023 = 64 tok x 16 ch8-chunks
    const int tok = c >> 4, ch8 = (c & 15) * 8;
    const float* wl = sh.a.wls[tok];
    float oacc[8];
    #pragma unroll
    for (int j = 0; j < 8; j++) oacc[j] = 0.f;
    #pragma unroll
    for (int s = 0; s < 4; s++) {
      int4 v = *(const int4*)(OP + ((size_t)(s * NBAT + b) * NTOK + t0 + tok) * NCS + ch8);
      const f16* a = (const f16*)&v;
      #pragma unroll
      for (int j = 0; j < 8; j++) oacc[j] += wl[s] * h2f(a[j]);
    }
    const float inv = wl[4];
    f16x8 r;
    #pragma unroll
    for (int j = 0; j < 8; j++) r[j] = f2h(oacc[j] * inv);
    *(f16x8*)&sh.a.Os[tok][ch8 ^ ((tok & 7) * 8)] = r;   // XOR-swizzled
  }
  __syncthreads();

  // phase B: MFMA from LDS fragments
  const int lane = tid & 63, w = tid >> 6, cc = lane & 31, hi = lane >> 5;
  const int th = w >> 1, oh = w & 1;
  f16x8 af[8];
  #pragma unroll
  for (int ks = 0; ks < 8; ks++) {
    const int t = th * 32 + cc;
    af[ks] = *(const f16x8*)&sh.a.Os[t][(ks * 16 + hi * 8) ^ ((t & 7) * 8)];
  }
  __syncthreads();   // all Os reads done; Es may overwrite

  f32x16 acc[4];
  #pragma unroll
  for (int nt = 0; nt < 4; nt++)
    #pragma unroll
    for (int i = 0; i < 16; i++) acc[nt][i] = 0.f;
  #pragma unroll
  for (int ks = 0; ks < 8; ks++)
    #pragma unroll
    for (int nt = 0; nt < 4; nt++) {
      f16x8 bw = *(const f16x8*)(wob + (size_t)(oh * 128 + nt * 32 + cc) * NCS + ks * 16 + hi * 8);
      acc[nt] = mfma32(af[ks], bw, acc[nt]);
    }
  #pragma unroll
  for (int nt = 0; nt < 4; nt++) {
    const int co = oh * 128 + nt * 32 + cc;
    const float bias = bo[co];
    float s = 0.f, sq = 0.f;
    #pragma unroll
    for (int i = 0; i < 16; i++) {
      float v = acc[nt][i] + bias;
      acc[nt][i] = v; s += v; sq += v * v;
    }
    s += __shfl_xor(s, 32); sq += __shfl_xor(sq, 32);
    if (hi == 0) {
      const size_t pi = ((size_t)(b * 64 + tt) * 2 + th) * NCH + co;
      Psum[pi * 2] = s; Psum[pi * 2 + 1] = sq;
    }
    #pragma unroll
    for (int q = 0; q < 4; q++) {
      f16x4 pk;
      #pragma unroll
      for (int j = 0; j < 4; j++) pk[j] = f2h(acc[nt][4 * q + j]);
      *(f16x4*)&sh.Es[co][th * 32 + q * 8 + hi * 4] = pk;
    }
  }
  __syncthreads();
  {
    const f16* er = &sh.Es[tid][0];
    f16* yp = Yb + ((size_t)b * NCH + tid) * NTOK + t0;
    #pragma unroll
    for (int p = 0; p < 8; p++)
      *(int4*)(yp + p * 8) = *(const int4*)(er + p * 8);
  }
}

// ---------------- 5: BN stats ----------------
__global__ void k_stats(const float* __restrict__ Psum, float* __restrict__ St) {
  const int ch = blockIdx.x, tid = threadIdx.x;
  float s = 0.f, sq = 0.f;
  for (int i = tid; i < 512; i += 128) {
    s  += Psum[((size_t)i * NCH + ch) * 2];
    sq += Psum[((size_t)i * NCH + ch) * 2 + 1];
  }
  #pragma unroll
  for (int off = 32; off >= 1; off >>= 1) { s += __shfl_down(s, off); sq += __shfl_down(sq, off); }
  __shared__ float red[4];
  if ((tid & 63) == 0) { red[(tid >> 6) * 2] = s; red[(tid >> 6) * 2 + 1] = sq; }
  __syncthreads();
  if (tid == 0) {
    s = red[0] + red[2]; sq = red[1] + red[3];
    const float mean = s * (1.f / 16384.f);
    const float var = sq * (1.f / 16384.f) - mean * mean;
    St[ch * 2] = mean;
    St[ch * 2 + 1] = 1.f / sqrtf(var + 1e-5f);
  }
}

// ---------------- 6: BN apply + ReLU + residual ----------------
__global__ void k_final(const f16* __restrict__ Yb, const float* __restrict__ x,
                        const float* __restrict__ St, const float* __restrict__ gamma,
                        const float* __restrict__ beta, float* __restrict__ out) {
  const size_t i = ((size_t)blockIdx.x * 256 + threadIdx.x) * 8;
  const int ch = (int)((i >> 12) & 255);
  const float mean = St[ch * 2], rstd = St[ch * 2 + 1];
  const float sc = gamma[ch] * rstd;
  const float sh = beta[ch] - mean * sc;
  int4 yv = *(const int4*)(Yb + i);
  const f16* ys = (const f16*)&yv;
  const float4 x0 = *(const float4*)(x + i);
  const float4 x1 = *(const float4*)(x + i + 4);
  float4 o0, o1;
  o0.x = fmaxf(h2f(ys[0]) * sc + sh, 0.f) + x0.x;
  o0.y = fmaxf(h2f(ys[1]) * sc + sh, 0.f) + x0.y;
  o0.z = fmaxf(h2f(ys[2]) * sc + sh, 0.f) + x0.z;
  o0.w = fmaxf(h2f(ys[3]) * sc + sh, 0.f) + x0.w;
  o1.x = fmaxf(h2f(ys[4]) * sc + sh, 0.f) + x1.x;
  o1.y = fmaxf(h2f(ys[5]) * sc + sh, 0.f) + x1.y;
  o1.z = fmaxf(h2f(ys[6]) * sc + sh, 0.f) + x1.z;
  o1.w = fmaxf(h2f(ys[7]) * sc + sh, 0.f) + x1.w;
  *(float4*)(out + i) = o0;
  *(float4*)(out + i + 4) = o1;
}

extern "C" void kernel_launch(void* const* d_in, const int* in_sizes, int n_in,
                              void* d_out, int out_size, void* d_ws, size_t ws_size,
                              hipStream_t stream) {
  const float* x     = (const float*)d_in[0];
  const float* Wq    = (const float*)d_in[1];
  const float* bq    = (const float*)d_in[2];
  const float* Wk    = (const float*)d_in[3];
  const float* bk    = (const float*)d_in[4];
  const float* Wv    = (const float*)d_in[5];
  const float* bv    = (const float*)d_in[6];
  const float* Wo    = (const float*)d_in[7];
  const float* bo    = (const float*)d_in[8];
  const float* gamma = (const float*)d_in[9];
  const float* beta  = (const float*)d_in[10];
  float* out = (float*)d_out;
  char* ws = (char*)d_ws;

  // ---- workspace layout (SPLIT=4 fixed; total ~31.2 MB) ----
  const size_t OFF_W  = 0;                      // 4 x 65536 B weight f16
  const size_t OFF_QT = 262144;
  const size_t OFF_KT = OFF_QT + 4194304;
  const size_t OFF_VC = OFF_KT + 4194304;
  const size_t OFF_OP = OFF_VC + 4194304;       // 12,845,056
  const size_t opsz = (size_t)4 * NBAT * NTOK * NCS * 2;    // 16.78 MB
  const size_t mlsz = (size_t)4 * NBAT * NTOK * 2 * 4;      // 0.52 MB
  const size_t OFF_ML = OFF_OP + opsz;
  const size_t OFF_PS = OFF_ML + mlsz;
  const size_t OFF_ST = OFF_PS + 1048576;

  f16* wqb = (f16*)(ws + OFF_W);
  f16* wkb = (f16*)(ws + OFF_W + 65536);
  f16* wvb = (f16*)(ws + OFF_W + 131072);
  f16* wob = (f16*)(ws + OFF_W + 196608);
  f16* Qt  = (f16*)(ws + OFF_QT);
  f16* Kt  = (f16*)(ws + OFF_KT);
  f16* Vc  = (f16*)(ws + OFF_VC);
  f16* OP  = (f16*)(ws + OFF_OP);
  float* ML = (float*)(ws + OFF_ML);
  float* Psum = (float*)(ws + OFF_PS);
  float* St   = (float*)(ws + OFF_ST);
  f16* Yb = (f16*)(ws + OFF_QT);   // alias: Qt+Kt dead after k_attn

  k_wconv<<<512, 256, 0, stream>>>(Wq, Wk, Wv, Wo, wqb);
  k_qkv<<<dim3(128, 4), 768, 0, stream>>>(x, wqb, wkb, wvb, bq, bk, bv, Qt, Kt, Vc);
  k_attn<<<dim3(16, 32), 256, 0, stream>>>(Qt, Kt, Vc, OP, ML, 16);
  k_out<<<dim3(64, 4), 256, 0, stream>>>(OP, ML, wob, bo, Yb, Psum);
  k_stats<<<256, 128, 0, stream>>>(Psum, St);
  k_final<<<2048, 256, 0, stream>>>(Yb, x, St, gamma, beta, out);
}